// Round 7
// baseline (2669.183 us; speedup 1.0000x reference)
//
#include <hip/hip_runtime.h>

// Problem constants
#define Bn   64
#define Pp   196
#define ENCd 2048
#define Hd   1024
#define Ad   1024
#define Ed   512
#define Vd   10000
#define TCd  32
#define Td   31
#define XHW  3584   // [emb 512 | awe 2048 | h 1024]
#define VPAD 10240  // W_fc padded rows
#define KHL  6144   // hi/lo concat K for init GEMM (3 x 2048)

typedef short bf16x8 __attribute__((ext_vector_type(8)));
typedef float f32x4  __attribute__((ext_vector_type(4)));

static __device__ __forceinline__ float bf2f(unsigned short u) {
    unsigned int x = ((unsigned int)u) << 16;
    float f; __builtin_memcpy(&f, &x, 4); return f;
}
static __device__ __forceinline__ unsigned short f2bf(float f) {
    unsigned int x; __builtin_memcpy(&x, &f, 4);
    x += 0x7fffu + ((x >> 16) & 1u);           // round-to-nearest-even
    return (unsigned short)(x >> 16);
}
static __device__ __forceinline__ float sigf(float x) { return 1.f / (1.f + expf(-x)); }

// async global->LDS, 16B per lane; LDS dest is wave-uniform base + lane*16
static __device__ __forceinline__ void gl_lds16(const unsigned short* g, unsigned short* l) {
    __builtin_amdgcn_global_load_lds((const __attribute__((address_space(1))) void*)g,
                                     (__attribute__((address_space(3))) void*)l,
                                     16, 0, 0);
}

// ---------------- precompute kernels ----------------

__global__ void sort_kernel(const int* __restrict__ lengths, const int* __restrict__ captions,
                            int* __restrict__ ind, int* __restrict__ dl,
                            float* __restrict__ out_caps, float* __restrict__ out_dl,
                            float* __restrict__ out_ind) {
    __shared__ int s_ind[Bn];
    int tid = threadIdx.x;
    int Lt = lengths[tid];
    int pos = 0;
    for (int k = 0; k < Bn; ++k) {
        int Lk = lengths[k];
        pos += (Lk > Lt) || (Lk == Lt && k < tid);
    }
    s_ind[pos] = tid;
    __syncthreads();
    int src = s_ind[tid];
    ind[tid] = src;
    int d = lengths[src] - 1;
    dl[tid] = d;
    out_ind[tid] = (float)src;
    out_dl[tid] = (float)d;
    for (int j = 0; j < TCd; ++j)
        out_caps[tid * TCd + j] = (float)captions[src * TCd + j];
}

__global__ void cvt_kernel(const float* __restrict__ src, unsigned short* __restrict__ dst, int n) {
    int i = blockIdx.x * 256 + threadIdx.x;
    int stride = gridDim.x * 256;
    for (; i < n; i += stride) dst[i] = f2bf(src[i]);
}

// Wcat gate-interleaved: new row r = 4*u+g holds original row g*1024+u of [W_ih|W_hh]
__global__ void wcat_kernel(const float* __restrict__ wih, const float* __restrict__ whh,
                            unsigned short* __restrict__ wcat) {
    int r = blockIdx.y;                         // new row 0..4095
    int idx = blockIdx.x * 256 + threadIdx.x;   // < 3584
    int js = (r & 3) * 1024 + (r >> 2);         // original row
    float v = (idx < 2560) ? wih[(size_t)js * 2560 + idx] : whh[(size_t)js * 1024 + (idx - 2560)];
    wcat[(size_t)r * XHW + idx] = f2bf(v);
}

// interleaved bias: bc[4u+g] = b_ih[g*1024+u] + b_hh[g*1024+u]
__global__ void biascat_kernel(const float* __restrict__ bih, const float* __restrict__ bhh,
                               float* __restrict__ bc) {
    int r = blockIdx.x * 256 + threadIdx.x;     // < 4096
    int js = (r & 3) * 1024 + (r >> 2);
    bc[r] = bih[js] + bhh[js];
}

__global__ void gather_eo_kernel(const float* __restrict__ enc_out, const int* __restrict__ ind,
                                 unsigned short* __restrict__ eo) {
    int b = blockIdx.y;
    int idx = blockIdx.x * 256 + threadIdx.x;   // < P*ENC = 401408
    int src = ind[b];
    eo[(size_t)b * (Pp * ENCd) + idx] = f2bf(enc_out[(size_t)src * (Pp * ENCd) + idx]);
}

// mean over P (fp32)
__global__ void mean_kernel(const float* __restrict__ enc_out, const int* __restrict__ ind,
                            float* __restrict__ meanf) {
    int b = blockIdx.y;
    int e = blockIdx.x * 256 + threadIdx.x;     // < 2048
    int src = ind[b];
    const float* base = enc_out + (size_t)src * (Pp * ENCd) + e;
    float s = 0.f;
    for (int p = 0; p < Pp; ++p) s += base[(size_t)p * ENCd];
    meanf[b * ENCd + e] = s * (1.f / 196.f);
}

// embeddings straight into per-step xh buffers (emb slot)
__global__ void embs_kernel(const float* __restrict__ emb, const int* __restrict__ captions,
                            const int* __restrict__ ind, unsigned short* __restrict__ xhbuf) {
    int b = blockIdx.y;
    int idx = blockIdx.x * 256 + threadIdx.x;   // < 31*512 = 15872
    int t = idx >> 9, e = idx & 511;
    int src = ind[b];
    int cap = captions[src * TCd + t];
    xhbuf[((size_t)t * Bn + b) * XHW + e] = f2bf(emb[(size_t)cap * Ed + e]);
}

// ---- init h0/c0 via hi/lo bf16 split-K GEMM (fp32-accurate) ----
// W' rows (2048 x 6144 bf16): [hi | hi | lo] of [W_init_h ; W_init_c]
__global__ void hilo_w_kernel(const float* __restrict__ winh, const float* __restrict__ winc,
                              unsigned short* __restrict__ dst) {
    int n = blockIdx.y;                          // 0..2047
    int k = blockIdx.x * 256 + threadIdx.x;      // 0..2047
    const float* src = (n < 1024) ? (winh + (size_t)n * ENCd)
                                  : (winc + (size_t)(n - 1024) * ENCd);
    float v = src[k];
    unsigned short hi = f2bf(v);
    unsigned short lo = f2bf(v - bf2f(hi));
    size_t row = (size_t)n * KHL;
    dst[row + k]        = hi;
    dst[row + 2048 + k] = hi;
    dst[row + 4096 + k] = lo;
}

// A' rows (64 x 6144 bf16): [hi | lo | hi] of meanf
__global__ void hilo_a_kernel(const float* __restrict__ meanf, unsigned short* __restrict__ dst) {
    int id = blockIdx.x * 256 + threadIdx.x;     // < 64*2048
    int m = id >> 11, k = id & 2047;
    float v = meanf[id];
    unsigned short hi = f2bf(v);
    unsigned short lo = f2bf(v - bf2f(hi));
    size_t row = (size_t)m * KHL;
    dst[row + k]        = hi;
    dst[row + 2048 + k] = lo;
    dst[row + 4096 + k] = hi;
}

// reduce split-K partials + bias -> xh0 (bf16 h slot) / cbuf (fp32)
__global__ void initred_kernel(const float* __restrict__ part,
                               const float* __restrict__ binh, const float* __restrict__ binc,
                               unsigned short* __restrict__ xh0, float* __restrict__ cbuf) {
    int id = blockIdx.x * 256 + threadIdx.x;     // < 64*2048
    int m = id >> 11, n = id & 2047;
    bool is_c = n >= 1024;
    int nn = is_c ? n - 1024 : n;
    float acc = is_c ? binc[nn] : binh[nn];
#pragma unroll
    for (int s = 0; s < 8; ++s)
        acc += part[((size_t)(s * Bn + m)) * 2048 + n];
    if (is_c) cbuf[(size_t)m * Hd + nn] = acc;
    else      xh0[(size_t)m * XHW + 2560 + nn] = f2bf(acc);
}

// ---------------- LDS-staged 128x128 tiled GEMM (m97 structure) ----------------
// C[m][n] = sum_k A[m][k]*W[n][k] (+ bias).  4 waves (2x2), each wave 64x64 (4x4 frags).
// EPI 1: bf16 out (ldo).  EPI 5: batched preds -> d_out with mask (m=t*64+b), n<N guard.
// SWZ 1: T1 XCD-aware block remap (requires gridDim.x % 8 == 0).
template<int EPI, int SWZ>
__global__ __launch_bounds__(256)
void gemm_tile(const unsigned short* __restrict__ A, int lda,
               const unsigned short* __restrict__ W, int ldw,
               const float* __restrict__ bias,
               int N, int nbn, int K,
               float* __restrict__ outf, unsigned short* __restrict__ outb, int ldo,
               const int* __restrict__ dl) {
    __shared__ unsigned short lA[128 * 32];
    __shared__ unsigned short lB[128 * 32];

    int tid  = threadIdx.x;
    int wave = tid >> 6, lane = tid & 63;
    int bid = blockIdx.x;
    if (SWZ) {
        int cpx = gridDim.x >> 3;               // blocks per XCD (grid % 8 == 0)
        bid = (bid & 7) * cpx + (bid >> 3);     // bijective XCD chunking
    }
    int mt = bid / nbn;
    int nt = bid % nbn;
    int m0 = mt * 128, n0 = nt * 128;

    int rs = lane >> 2;
    int cs = (lane & 3) * 8;
    const unsigned short* aG0 = A + (size_t)(m0 + wave * 16 + rs) * lda + cs;
    const unsigned short* aG1 = aG0 + (size_t)64 * lda;
    const unsigned short* bG0 = W + (size_t)(n0 + wave * 16 + rs) * ldw + cs;
    const unsigned short* bG1 = bG0 + (size_t)64 * ldw;
    unsigned short* lA0 = &lA[(wave * 16) * 32];
    unsigned short* lA1 = &lA[(64 + wave * 16) * 32];
    unsigned short* lB0 = &lB[(wave * 16) * 32];
    unsigned short* lB1 = &lB[(64 + wave * 16) * 32];

    int wr = wave >> 1, wc = wave & 1;          // 2x2 wave grid
    int col = lane & 15, quad = lane >> 4;

    f32x4 acc[4][4];
#pragma unroll
    for (int i = 0; i < 4; ++i)
#pragma unroll
        for (int j = 0; j < 4; ++j) acc[i][j] = (f32x4){0.f, 0.f, 0.f, 0.f};

    for (int kt = 0; kt < K; kt += 32) {
        __syncthreads();                        // prev compute done reading LDS
        gl_lds16(aG0 + kt, lA0);
        gl_lds16(aG1 + kt, lA1);
        gl_lds16(bG0 + kt, lB0);
        gl_lds16(bG1 + kt, lB1);
        __syncthreads();                        // drain before barrier -> tiles ready

        bf16x8 af[4], bf[4];
#pragma unroll
        for (int i = 0; i < 4; ++i) {
            af[i] = *(const bf16x8*)&lA[(wr * 64 + i * 16 + col) * 32 + quad * 8];
            bf[i] = *(const bf16x8*)&lB[(wc * 64 + i * 16 + col) * 32 + quad * 8];
        }
#pragma unroll
        for (int mi = 0; mi < 4; ++mi)
#pragma unroll
            for (int nj = 0; nj < 4; ++nj)
                acc[mi][nj] = __builtin_amdgcn_mfma_f32_16x16x32_bf16(af[mi], bf[nj], acc[mi][nj], 0, 0, 0);
    }

#pragma unroll
    for (int mi = 0; mi < 4; ++mi) {
#pragma unroll
        for (int r = 0; r < 4; ++r) {
            int m = m0 + wr * 64 + mi * 16 + quad * 4 + r;
            if (EPI == 5 && m >= Td * Bn) continue;
#pragma unroll
            for (int nj = 0; nj < 4; ++nj) {
                int n = n0 + wc * 64 + nj * 16 + col;
                if (EPI == 1) {
                    outb[(size_t)m * ldo + n] = f2bf(acc[mi][nj][r] + bias[n]);
                } else {
                    if (n < N) {
                        int t = m >> 6, b = m & 63;
                        float mf = (t < dl[b]) ? 1.f : 0.f;
                        float v = acc[mi][nj][r] + bias[n];
                        outf[((size_t)b * Td + t) * Vd + n] = v * mf;
                    }
                }
            }
        }
    }
}

// ---------------- split-K skinny GEMM (M=64 in one wave tile) ----------------
// part[s][m][n] = sum_{k in chunk s} A[m][k]*W[n][k]
template<int SK>
__global__ void gemm_sk4(const unsigned short* __restrict__ A, int lda,
                         const unsigned short* __restrict__ W,
                         int N, int K, float* __restrict__ part) {
    int wid  = (blockIdx.x * 256 + threadIdx.x) >> 6;
    int lane = threadIdx.x & 63;
    int ntiles = N >> 4;
    int s = wid / ntiles;
    int nt = wid - s * ntiles;
    int col = lane & 15, quad = lane >> 4;
    int kLen = K / SK, k0 = s * kLen;

    const unsigned short* aptr = A + (size_t)col * lda + k0 + quad * 8;
    const unsigned short* wptr = W + (size_t)(nt * 16 + col) * K + k0 + quad * 8;

    f32x4 acc[4];
#pragma unroll
    for (int i = 0; i < 4; ++i) acc[i] = (f32x4){0.f, 0.f, 0.f, 0.f};

    for (int k = 0; k < kLen; k += 32) {
        bf16x8 wf = *(const bf16x8*)(wptr + k);
#pragma unroll
        for (int mi = 0; mi < 4; ++mi) {
            bf16x8 af = *(const bf16x8*)(aptr + (size_t)mi * 16 * lda + k);
            acc[mi] = __builtin_amdgcn_mfma_f32_16x16x32_bf16(af, wf, acc[mi], 0, 0, 0);
        }
    }

    int n = nt * 16 + col;
    float* base = part + (size_t)s * Bn * N;
#pragma unroll
    for (int mi = 0; mi < 4; ++mi) {
#pragma unroll
        for (int r = 0; r < 4; ++r) {
            int m = mi * 16 + quad * 4 + r;
            base[(size_t)m * N + n] = acc[mi][r];
        }
    }
}

// ---------------- per-step kernels ----------------

// scores: fuses dec split-K reduction (+bias) in LDS, then relu-dot
__global__ void scores_kernel(const float* __restrict__ pdb, const float* __restrict__ bdec,
                              const unsigned short* __restrict__ encatt,
                              const float* __restrict__ wfull,
                              float* __restrict__ scores) {
    int b = blockIdx.y;
    int tid = threadIdx.x;
    __shared__ float sdec[Ad];
    for (int i = tid; i < Ad; i += 256) {
        float v = bdec[i];
#pragma unroll
        for (int s2 = 0; s2 < 4; ++s2) v += pdb[((size_t)(s2 * Bn + b)) * 3072 + i];
        sdec[i] = v;
    }
    __syncthreads();
    int wave = tid >> 6, lane = tid & 63;
    int p = blockIdx.x * 4 + wave;              // 49*4 = 196
    const unsigned int* ea = (const unsigned int*)(encatt + ((size_t)(b * Pp + p) << 10));
    const float2* dp = (const float2*)sdec;
    const float2* wf = (const float2*)wfull;
    float acc = 0.f;
#pragma unroll
    for (int it = 0; it < 8; ++it) {
        int i2 = it * 64 + lane;
        unsigned int u = ea[i2];
        float2 dv = dp[i2];
        float2 wv = wf[i2];
        acc += fmaxf(bf2f((unsigned short)(u & 0xffffu)) + dv.x, 0.f) * wv.x;
        acc += fmaxf(bf2f((unsigned short)(u >> 16)) + dv.y, 0.f) * wv.y;
    }
    for (int o2 = 32; o2; o2 >>= 1) acc += __shfl_xor(acc, o2);
    if (lane == 0) scores[b * Pp + p] = acc;
}

// softmax (redundant per e-slice) + context + gate(reduce+sigmoid) + awe -> xh[t]
__global__ void softmaxctx_kernel(const float* __restrict__ scores,
                                  const float* __restrict__ pdb, const float* __restrict__ bbeta,
                                  const unsigned short* __restrict__ eo,
                                  unsigned short* __restrict__ xh_t,
                                  float* __restrict__ out_alpha,
                                  const int* __restrict__ dl, int t) {
    int b = blockIdx.y, tid = threadIdx.x;
    __shared__ float red[256];
    __shared__ float sal[Pp];
    float s = (tid < Pp) ? scores[b * Pp + tid] : -1e30f;
    red[tid] = s; __syncthreads();
    for (int o2 = 128; o2; o2 >>= 1) { if (tid < o2) red[tid] = fmaxf(red[tid], red[tid + o2]); __syncthreads(); }
    float mx = red[0]; __syncthreads();
    float e = (tid < Pp) ? expf(s - mx) : 0.f;
    red[tid] = e; __syncthreads();
    for (int o2 = 128; o2; o2 >>= 1) { if (tid < o2) red[tid] += red[tid + o2]; __syncthreads(); }
    float inv = 1.f / red[0];
    if (tid < Pp) {
        float a = e * inv;
        sal[tid] = a;
        if (blockIdx.x == 0) {
            float mf = (t < dl[b]) ? 1.f : 0.f;
            out_alpha[((size_t)b * Td + t) * Pp + tid] = a * mf;
        }
    }
    __syncthreads();

    int e0 = blockIdx.x * 512 + tid * 2;
    const unsigned int* base = (const unsigned int*)(eo + (size_t)b * Pp * ENCd);
    int half = e0 >> 1;
    float a0 = 0.f, a1 = 0.f;
    for (int p = 0; p < Pp; ++p) {
        unsigned int u = base[p * (ENCd / 2) + half];
        float w = sal[p];
        a0 += w * bf2f((unsigned short)(u & 0xffffu));
        a1 += w * bf2f((unsigned short)(u >> 16));
    }
    float g0 = bbeta[e0], g1 = bbeta[e0 + 1];
#pragma unroll
    for (int s2 = 0; s2 < 4; ++s2) {
        const float* pb = pdb + ((size_t)(s2 * Bn + b)) * 3072 + Ad + e0;
        g0 += pb[0]; g1 += pb[1];
    }
    g0 = sigf(g0); g1 = sigf(g1);
    xh_t[(size_t)b * XHW + 512 + e0]     = f2bf(a0 * g0);
    xh_t[(size_t)b * XHW + 512 + e0 + 1] = f2bf(a1 * g1);
}

// ---- fused gates GEMM (full-K, half-K per wave pair) + LSTM pointwise ----
// wg rows gate-interleaved (row 4u+g), K = XHW.  grid 128 x 256.
// block covers 8 units (32 rows): wave w -> ntb = w&1 (16 rows), khalf = w>>1.
__global__ __launch_bounds__(256)
void gates_lstm_kernel(const unsigned short* __restrict__ xh_cur,
                       const unsigned short* __restrict__ wg,
                       const float* __restrict__ bg,
                       float* __restrict__ c,
                       unsigned short* __restrict__ xh_next,
                       unsigned short* __restrict__ hall,
                       const int* __restrict__ dl, int t) {
    __shared__ float lacc[4][64][16];           // [wave][b][col] 16 KB
    int tid = threadIdx.x;
    int wave = tid >> 6, lane = tid & 63;
    int col = lane & 15, quad = lane >> 4;
    int ntb = wave & 1, kh = wave >> 1;
    int n0 = blockIdx.x * 32 + ntb * 16;        // interleaved row base
    int k0 = kh * (XHW / 2);                    // 0 or 1792

    const unsigned short* aptr = xh_cur + (size_t)col * XHW + k0 + quad * 8;
    const unsigned short* wptr = wg + (size_t)(n0 + col) * XHW + k0 + quad * 8;

    f32x4 acc[4];
#pragma unroll
    for (int i = 0; i < 4; ++i) acc[i] = (f32x4){0.f, 0.f, 0.f, 0.f};

    for (int k = 0; k < XHW / 2; k += 32) {
        bf16x8 wf = *(const bf16x8*)(wptr + k);
#pragma unroll
        for (int mi = 0; mi < 4; ++mi) {
            bf16x8 af = *(const bf16x8*)(aptr + (size_t)mi * 16 * XHW + k);
            acc[mi] = __builtin_amdgcn_mfma_f32_16x16x32_bf16(af, wf, acc[mi], 0, 0, 0);
        }
    }
#pragma unroll
    for (int mi = 0; mi < 4; ++mi)
#pragma unroll
        for (int r = 0; r < 4; ++r)
            lacc[wave][mi * 16 + quad * 4 + r][col] = acc[mi][r];
    __syncthreads();

#pragma unroll
    for (int it = 0; it < 2; ++it) {
        int pid = tid + it * 256;               // 0..511 = 64 b x 8 units
        int b = pid >> 3;
        int ub = pid & 7;                       // unit within block
        int w0 = ub >> 2;                       // ntb wave (partner w0+2 has khalf 1)
        int cb = (ub & 3) * 4;                  // col base of the 4 gates
        int j = blockIdx.x * 8 + ub;            // global unit 0..1023
        float i_ = bg[4 * j + 0] + (lacc[w0][b][cb + 0] + lacc[w0 + 2][b][cb + 0]);
        float f_ = bg[4 * j + 1] + (lacc[w0][b][cb + 1] + lacc[w0 + 2][b][cb + 1]);
        float g_ = bg[4 * j + 2] + (lacc[w0][b][cb + 2] + lacc[w0 + 2][b][cb + 2]);
        float o_ = bg[4 * j + 3] + (lacc[w0][b][cb + 3] + lacc[w0 + 2][b][cb + 3]);
        float co = c[b * Hd + j];
        float cn = sigf(f_) * co + sigf(i_) * tanhf(g_);
        float hn = sigf(o_) * tanhf(cn);
        bool m = t < dl[b];
        float ho = bf2f(xh_cur[(size_t)b * XHW + 2560 + j]);
        c[b * Hd + j] = m ? cn : co;
        xh_next[(size_t)b * XHW + 2560 + j] = f2bf(m ? hn : ho);
        hall[((size_t)t * Bn + b) * Hd + j] = f2bf(hn);     // row m = t*64+b
    }
}

// ---------------- host ----------------

extern "C" void kernel_launch(void* const* d_in, const int* in_sizes, int n_in,
                              void* d_out, int out_size, void* d_ws, size_t ws_size,
                              hipStream_t stream) {
    const float* enc_out   = (const float*)d_in[0];
    const int*   captions  = (const int*)d_in[1];
    const int*   lengths   = (const int*)d_in[2];
    const float* W_enc_att = (const float*)d_in[3];
    const float* b_enc_att = (const float*)d_in[4];
    const float* W_dec_att = (const float*)d_in[5];
    const float* b_dec_att = (const float*)d_in[6];
    const float* W_full    = (const float*)d_in[7];
    const float* emb       = (const float*)d_in[9];
    const float* W_ih      = (const float*)d_in[10];
    const float* b_ih      = (const float*)d_in[11];
    const float* W_hh      = (const float*)d_in[12];
    const float* b_hh      = (const float*)d_in[13];
    const float* W_init_h  = (const float*)d_in[14];
    const float* b_init_h  = (const float*)d_in[15];
    const float* W_init_c  = (const float*)d_in[16];
    const float* b_init_c  = (const float*)d_in[17];
    const float* W_beta    = (const float*)d_in[18];
    const float* b_beta    = (const float*)d_in[19];
    const float* W_fc      = (const float*)d_in[20];
    const float* b_fc      = (const float*)d_in[21];

    float* out       = (float*)d_out;
    float* out_pred  = out;                                    // (B,T,V)
    float* out_alpha = out + (size_t)Bn * Td * Vd;             // (B,T,P)
    float* out_caps  = out_alpha + (size_t)Bn * Td * Pp;       // (B,TC)
    float* out_dl    = out_caps + (size_t)Bn * TCd;            // (B,)
    float* out_ind   = out_dl + Bn;                            // (B,)

    char* ws = (char*)d_ws;
    size_t off = 0;
    auto take = [&](size_t n) -> char* {
        char* p = ws + off;
        off = (off + n + 255) & ~(size_t)255;
        return p;
    };
    int* ind_i   = (int*)take(Bn * 4);
    int* dl_i    = (int*)take(Bn * 4);
    unsigned short* eo_b     = (unsigned short*)take((size_t)Bn * Pp * ENCd * 2);   // 51.4 MB
    unsigned short* encatt_b = (unsigned short*)take((size_t)Bn * Pp * Ad * 2);     // 25.7 MB
    unsigned short* wcat_b   = (unsigned short*)take((size_t)4096 * XHW * 2);       // 29.4 MB
    unsigned short* wfc_b    = (unsigned short*)take((size_t)VPAD * Hd * 2);        // 21.0 MB (padded)
    unsigned short* wenc_b   = (unsigned short*)take((size_t)Ad * ENCd * 2);        // 8.4 MB
    unsigned short* wdb_b    = (unsigned short*)take((size_t)3072 * Hd * 2);        // 6.3 MB [wdec;wbeta]
    float*          biascat  = (float*)take(4096 * 4);
    float*          meanf    = (float*)take((size_t)Bn * ENCd * 4);
    unsigned short* xhbuf    = (unsigned short*)take((size_t)32 * Bn * XHW * 2);    // 14.7 MB
    float*          cbuf     = (float*)take((size_t)Bn * Hd * 4);
    unsigned short* hall     = (unsigned short*)take((size_t)2048 * Hd * 2);        // 4.2 MB (rows 1984..2047 pad)
    float*          scores   = (float*)take((size_t)Bn * Pp * 4);
    float*          pdb      = (float*)take((size_t)4 * Bn * 3072 * 4);             // 3.1 MB
    float*          pinit    = (float*)take((size_t)8 * Bn * 2048 * 4);             // 4.2 MB (init partials)
    unsigned short* ahl      = (unsigned short*)take((size_t)Bn * KHL * 2);         // 0.8 MB
    // alias (stream-ordered, lifetime-disjoint):
    unsigned short* whl   = encatt_b;   // 25.2 MB needed <= 25.7 MB; overwritten later by enc_att GEMM
    (void)ws_size; (void)out_size; (void)n_in; (void)in_sizes;

    // ---- precompute ----
    sort_kernel<<<1, 64, 0, stream>>>(lengths, captions, ind_i, dl_i, out_caps, out_dl, out_ind);

    auto cvt = [&](const float* s, unsigned short* d, int n) {
        int g = (n + 255) / 256; if (g > 4096) g = 4096;
        cvt_kernel<<<g, 256, 0, stream>>>(s, d, n);
    };
    cvt(W_enc_att, wenc_b, Ad * ENCd);
    cvt(W_dec_att, wdb_b, Ad * Hd);                         // rows 0..1023
    cvt(W_beta,  wdb_b + (size_t)Ad * Hd, ENCd * Hd);       // rows 1024..3071
    cvt(W_fc,    wfc_b,   Vd * Hd);                         // rows 10000..10239 stay garbage (cols unused)
    wcat_kernel<<<dim3(14, 4096), 256, 0, stream>>>(W_ih, W_hh, wcat_b);
    biascat_kernel<<<16, 256, 0, stream>>>(b_ih, b_hh, biascat);

    gather_eo_kernel<<<dim3(1568, Bn), 256, 0, stream>>>(enc_out, ind_i, eo_b);
    mean_kernel<<<dim3(8, Bn), 256, 0, stream>>>(enc_out, ind_i, meanf);
    embs_kernel<<<dim3(62, Bn), 256, 0, stream>>>(emb, captions, ind_i, xhbuf);

    // h0/c0: hi/lo bf16 split-K GEMM (A'=[hi|lo|hi] 64xKHL, W'=[hi|hi|lo] 2048xKHL)
    hilo_w_kernel<<<dim3(8, 2048), 256, 0, stream>>>(W_init_h, W_init_c, whl);
    hilo_a_kernel<<<512, 256, 0, stream>>>(meanf, ahl);
    gemm_sk4<8><<<256, 256, 0, stream>>>(ahl, KHL, whl, 2048, KHL, pinit);
    initred_kernel<<<512, 256, 0, stream>>>(pinit, b_init_h, b_init_c, xhbuf, cbuf);

    // enc_att = eo @ W_enc_att^T + b -> bf16.  M=12544 (98 x 128-tiles), N=1024 (8 tiles)
    // SWZ=1: chunked XCD swizzle (FETCH 204 -> 48 MB verified round 6)
    gemm_tile<1, 1><<<98 * 8, 256, 0, stream>>>(eo_b, ENCd, wenc_b, ENCd, b_enc_att,
        Ad, 8, ENCd, nullptr, encatt_b, Ad, nullptr);

    // ---- time loop ----
    for (int t = 0; t < Td; ++t) {
        unsigned short* xh_t = xhbuf + (size_t)t * Bn * XHW;
        unsigned short* xh_n = xhbuf + (size_t)(t + 1) * Bn * XHW;

        // [dec | gate] partials: A = h slot, W = [wdec; wbeta], N=3072, K=1024, SK=4
        gemm_sk4<4><<<192, 256, 0, stream>>>(xh_t + 2560, XHW, wdb_b, 3072, Hd, pdb);

        scores_kernel<<<dim3(49, Bn), 256, 0, stream>>>(pdb, b_dec_att, encatt_b, W_full, scores);

        softmaxctx_kernel<<<dim3(4, Bn), 256, 0, stream>>>(scores, pdb, b_beta, eo_b,
            xh_t, out_alpha, dl_i, t);

        // fused gates GEMM + LSTM (interleaved wcat, no pgates round-trip)
        gates_lstm_kernel<<<128, 256, 0, stream>>>(xh_t, wcat_b, biascat, cbuf,
            xh_n, hall, dl_i, t);
    }

    // batched preds: hall (2048 x 1024, rows m=t*64+b) @ W_fc^T -> d_out with mask
    // M=2048 (16 x 128-tiles), N=10000 -> 80 x 128-tiles over padded 10240.
    // SWZ=0: nbn=80 default map already pins each B-panel to one XCD.
    gemm_tile<5, 0><<<16 * 80, 256, 0, stream>>>(hall, Hd, wfc_b, Hd, b_fc,
        Vd, 80, Hd, out_pred, nullptr, 0, dl_i);
}

// Round 8
// 2097.968 us; speedup vs baseline: 1.2723x; 1.2723x over previous
//
#include <hip/hip_runtime.h>

// Problem constants
#define Bn   64
#define Pp   196
#define ENCd 2048
#define Hd   1024
#define Ad   1024
#define Ed   512
#define Vd   10000
#define TCd  32
#define Td   31
#define XHW  3584   // [emb 512 | awe 2048 | h 1024]
#define VPAD 10240  // W_fc padded rows
#define KHL  6144   // hi/lo concat K for init GEMM (3 x 2048)

typedef short bf16x8 __attribute__((ext_vector_type(8)));
typedef float f32x4  __attribute__((ext_vector_type(4)));

static __device__ __forceinline__ float bf2f(unsigned short u) {
    unsigned int x = ((unsigned int)u) << 16;
    float f; __builtin_memcpy(&f, &x, 4); return f;
}
static __device__ __forceinline__ unsigned short f2bf(float f) {
    unsigned int x; __builtin_memcpy(&x, &f, 4);
    x += 0x7fffu + ((x >> 16) & 1u);           // round-to-nearest-even
    return (unsigned short)(x >> 16);
}
static __device__ __forceinline__ float sigf(float x) { return 1.f / (1.f + expf(-x)); }

// async global->LDS, 16B per lane; LDS dest is wave-uniform base + lane*16
static __device__ __forceinline__ void gl_lds16(const unsigned short* g, unsigned short* l) {
    __builtin_amdgcn_global_load_lds((const __attribute__((address_space(1))) void*)g,
                                     (__attribute__((address_space(3))) void*)l,
                                     16, 0, 0);
}

// ---------------- precompute kernels ----------------

__global__ void sort_kernel(const int* __restrict__ lengths, const int* __restrict__ captions,
                            int* __restrict__ ind, int* __restrict__ dl,
                            float* __restrict__ out_caps, float* __restrict__ out_dl,
                            float* __restrict__ out_ind, int* __restrict__ nact) {
    __shared__ int s_ind[Bn];
    __shared__ int s_dl[Bn];
    int tid = threadIdx.x;
    int Lt = lengths[tid];
    int pos = 0;
    for (int k = 0; k < Bn; ++k) {
        int Lk = lengths[k];
        pos += (Lk > Lt) || (Lk == Lt && k < tid);
    }
    s_ind[pos] = tid;
    __syncthreads();
    int src = s_ind[tid];
    ind[tid] = src;
    int d = lengths[src] - 1;
    dl[tid] = d;
    s_dl[tid] = d;
    out_ind[tid] = (float)src;
    out_dl[tid] = (float)d;
    for (int j = 0; j < TCd; ++j)
        out_caps[tid * TCd + j] = (float)captions[src * TCd + j];
    __syncthreads();
    if (tid < Td) {
        int cnt = 0;
        for (int b = 0; b < Bn; ++b) cnt += (s_dl[b] > tid) ? 1 : 0;
        nact[tid] = cnt;                         // sorted desc => active batches are b < nact[t]
    }
}

__global__ void zero_alpha_kernel(float* __restrict__ a, int n) {
    int i = blockIdx.x * 256 + threadIdx.x;
    if (i < n) a[i] = 0.f;
}

__global__ void cvt_kernel(const float* __restrict__ src, unsigned short* __restrict__ dst, int n) {
    int i = blockIdx.x * 256 + threadIdx.x;
    int stride = gridDim.x * 256;
    for (; i < n; i += stride) dst[i] = f2bf(src[i]);
}

// Wcat = [W_ih | W_hh]  (4096 x 3584) bf16
__global__ void wcat_kernel(const float* __restrict__ wih, const float* __restrict__ whh,
                            unsigned short* __restrict__ wcat) {
    int j = blockIdx.y;
    int idx = blockIdx.x * 256 + threadIdx.x;   // < 3584
    float v = (idx < 2560) ? wih[(size_t)j * 2560 + idx] : whh[(size_t)j * 1024 + (idx - 2560)];
    wcat[(size_t)j * XHW + idx] = f2bf(v);
}

__global__ void biascat_kernel(const float* __restrict__ bih, const float* __restrict__ bhh,
                               float* __restrict__ bc) {
    int i = blockIdx.x * 256 + threadIdx.x;     // < 4096
    bc[i] = bih[i] + bhh[i];
}

__global__ void gather_eo_kernel(const float* __restrict__ enc_out, const int* __restrict__ ind,
                                 unsigned short* __restrict__ eo) {
    int b = blockIdx.y;
    int idx = blockIdx.x * 256 + threadIdx.x;   // < P*ENC = 401408
    int src = ind[b];
    eo[(size_t)b * (Pp * ENCd) + idx] = f2bf(enc_out[(size_t)src * (Pp * ENCd) + idx]);
}

// mean over P (fp32)
__global__ void mean_kernel(const float* __restrict__ enc_out, const int* __restrict__ ind,
                            float* __restrict__ meanf) {
    int b = blockIdx.y;
    int e = blockIdx.x * 256 + threadIdx.x;     // < 2048
    int src = ind[b];
    const float* base = enc_out + (size_t)src * (Pp * ENCd) + e;
    float s = 0.f;
    for (int p = 0; p < Pp; ++p) s += base[(size_t)p * ENCd];
    meanf[b * ENCd + e] = s * (1.f / 196.f);
}

// embeddings straight into per-step xh buffers (emb slot)
__global__ void embs_kernel(const float* __restrict__ emb, const int* __restrict__ captions,
                            const int* __restrict__ ind, unsigned short* __restrict__ xhbuf) {
    int b = blockIdx.y;
    int idx = blockIdx.x * 256 + threadIdx.x;   // < 31*512 = 15872
    int t = idx >> 9, e = idx & 511;
    int src = ind[b];
    int cap = captions[src * TCd + t];
    xhbuf[((size_t)t * Bn + b) * XHW + e] = f2bf(emb[(size_t)cap * Ed + e]);
}

// ---- init h0/c0 via hi/lo bf16 split-K GEMM (fp32-accurate) ----
// W' rows (2048 x 6144 bf16): [hi | hi | lo] of [W_init_h ; W_init_c]
__global__ void hilo_w_kernel(const float* __restrict__ winh, const float* __restrict__ winc,
                              unsigned short* __restrict__ dst) {
    int n = blockIdx.y;                          // 0..2047
    int k = blockIdx.x * 256 + threadIdx.x;      // 0..2047
    const float* src = (n < 1024) ? (winh + (size_t)n * ENCd)
                                  : (winc + (size_t)(n - 1024) * ENCd);
    float v = src[k];
    unsigned short hi = f2bf(v);
    unsigned short lo = f2bf(v - bf2f(hi));
    size_t row = (size_t)n * KHL;
    dst[row + k]        = hi;
    dst[row + 2048 + k] = hi;
    dst[row + 4096 + k] = lo;
}

// A' rows (64 x 6144 bf16): [hi | lo | hi] of meanf
__global__ void hilo_a_kernel(const float* __restrict__ meanf, unsigned short* __restrict__ dst) {
    int id = blockIdx.x * 256 + threadIdx.x;     // < 64*2048
    int m = id >> 11, k = id & 2047;
    float v = meanf[id];
    unsigned short hi = f2bf(v);
    unsigned short lo = f2bf(v - bf2f(hi));
    size_t row = (size_t)m * KHL;
    dst[row + k]        = hi;
    dst[row + 2048 + k] = lo;
    dst[row + 4096 + k] = hi;
}

// reduce split-K partials + bias -> xh0 (bf16 h slot) / cbuf (fp32)
__global__ void initred_kernel(const float* __restrict__ part,
                               const float* __restrict__ binh, const float* __restrict__ binc,
                               unsigned short* __restrict__ xh0, float* __restrict__ cbuf) {
    int id = blockIdx.x * 256 + threadIdx.x;     // < 64*2048
    int m = id >> 11, n = id & 2047;
    bool is_c = n >= 1024;
    int nn = is_c ? n - 1024 : n;
    float acc = is_c ? binc[nn] : binh[nn];
#pragma unroll
    for (int s = 0; s < 8; ++s)
        acc += part[((size_t)(s * Bn + m)) * 2048 + n];
    if (is_c) cbuf[(size_t)m * Hd + nn] = acc;
    else      xh0[(size_t)m * XHW + 2560 + nn] = f2bf(acc);
}

// ---------------- LDS-staged 128x128 tiled GEMM (m97 structure) ----------------
// C[m][n] = sum_k A[m][k]*W[n][k] (+ bias).  4 waves (2x2), each wave 64x64 (4x4 frags).
// EPI 1: bf16 out (ldo).  EPI 5: batched preds -> d_out, select-masked (m=t*64+b), n<N guard.
// SWZ 1: T1 XCD-aware block remap (requires gridDim.x % 8 == 0).
template<int EPI, int SWZ>
__global__ __launch_bounds__(256)
void gemm_tile(const unsigned short* __restrict__ A, int lda,
               const unsigned short* __restrict__ W, int ldw,
               const float* __restrict__ bias,
               int N, int nbn, int K,
               float* __restrict__ outf, unsigned short* __restrict__ outb, int ldo,
               const int* __restrict__ dl) {
    __shared__ unsigned short lA[128 * 32];
    __shared__ unsigned short lB[128 * 32];

    int tid  = threadIdx.x;
    int wave = tid >> 6, lane = tid & 63;
    int bid = blockIdx.x;
    if (SWZ) {
        int cpx = gridDim.x >> 3;               // blocks per XCD (grid % 8 == 0)
        bid = (bid & 7) * cpx + (bid >> 3);     // bijective XCD chunking
    }
    int mt = bid / nbn;
    int nt = bid % nbn;
    int m0 = mt * 128, n0 = nt * 128;

    int rs = lane >> 2;
    int cs = (lane & 3) * 8;
    const unsigned short* aG0 = A + (size_t)(m0 + wave * 16 + rs) * lda + cs;
    const unsigned short* aG1 = aG0 + (size_t)64 * lda;
    const unsigned short* bG0 = W + (size_t)(n0 + wave * 16 + rs) * ldw + cs;
    const unsigned short* bG1 = bG0 + (size_t)64 * ldw;
    unsigned short* lA0 = &lA[(wave * 16) * 32];
    unsigned short* lA1 = &lA[(64 + wave * 16) * 32];
    unsigned short* lB0 = &lB[(wave * 16) * 32];
    unsigned short* lB1 = &lB[(64 + wave * 16) * 32];

    int wr = wave >> 1, wc = wave & 1;          // 2x2 wave grid
    int col = lane & 15, quad = lane >> 4;

    f32x4 acc[4][4];
#pragma unroll
    for (int i = 0; i < 4; ++i)
#pragma unroll
        for (int j = 0; j < 4; ++j) acc[i][j] = (f32x4){0.f, 0.f, 0.f, 0.f};

    for (int kt = 0; kt < K; kt += 32) {
        __syncthreads();                        // prev compute done reading LDS
        gl_lds16(aG0 + kt, lA0);
        gl_lds16(aG1 + kt, lA1);
        gl_lds16(bG0 + kt, lB0);
        gl_lds16(bG1 + kt, lB1);
        __syncthreads();                        // drain before barrier -> tiles ready

        bf16x8 af[4], bf[4];
#pragma unroll
        for (int i = 0; i < 4; ++i) {
            af[i] = *(const bf16x8*)&lA[(wr * 64 + i * 16 + col) * 32 + quad * 8];
            bf[i] = *(const bf16x8*)&lB[(wc * 64 + i * 16 + col) * 32 + quad * 8];
        }
#pragma unroll
        for (int mi = 0; mi < 4; ++mi)
#pragma unroll
            for (int nj = 0; nj < 4; ++nj)
                acc[mi][nj] = __builtin_amdgcn_mfma_f32_16x16x32_bf16(af[mi], bf[nj], acc[mi][nj], 0, 0, 0);
    }

#pragma unroll
    for (int mi = 0; mi < 4; ++mi) {
#pragma unroll
        for (int r = 0; r < 4; ++r) {
            int m = m0 + wr * 64 + mi * 16 + quad * 4 + r;
            if (EPI == 5 && m >= Td * Bn) continue;
#pragma unroll
            for (int nj = 0; nj < 4; ++nj) {
                int n = n0 + wc * 64 + nj * 16 + col;
                if (EPI == 1) {
                    outb[(size_t)m * ldo + n] = f2bf(acc[mi][nj][r] + bias[n]);
                } else {
                    if (n < N) {
                        int t = m >> 6, b = m & 63;
                        // select form: inactive rows (hall unwritten) must yield exact 0
                        float v = acc[mi][nj][r] + bias[n];
                        outf[((size_t)b * Td + t) * Vd + n] = (t < dl[b]) ? v : 0.f;
                    }
                }
            }
        }
    }
}

// ---------------- split-K skinny GEMM (M=64 in one wave tile) ----------------
// part[s][m][n] = sum_{k in chunk s} A[m][k]*W[n][k]
// nact (optional): clamp m-tiles to ceil(nact[t]/16) (sorted active batches)
template<int SK>
__global__ void gemm_sk4(const unsigned short* __restrict__ A, int lda,
                         const unsigned short* __restrict__ W,
                         int N, int K, float* __restrict__ part,
                         const int* __restrict__ nact, int t) {
    int mtn = 4;
    if (nact) mtn = (nact[t] + 15) >> 4;
    int wid  = (blockIdx.x * 256 + threadIdx.x) >> 6;
    int lane = threadIdx.x & 63;
    int ntiles = N >> 4;
    int s = wid / ntiles;
    int nt = wid - s * ntiles;
    int col = lane & 15, quad = lane >> 4;
    int kLen = K / SK, k0 = s * kLen;

    const unsigned short* aptr = A + (size_t)col * lda + k0 + quad * 8;
    const unsigned short* wptr = W + (size_t)(nt * 16 + col) * K + k0 + quad * 8;

    f32x4 acc[4];
#pragma unroll
    for (int i = 0; i < 4; ++i) acc[i] = (f32x4){0.f, 0.f, 0.f, 0.f};

    for (int k = 0; k < kLen; k += 32) {
        bf16x8 wf = *(const bf16x8*)(wptr + k);
#pragma unroll
        for (int mi = 0; mi < 4; ++mi) {
            if (mi < mtn) {
                bf16x8 af = *(const bf16x8*)(aptr + (size_t)mi * 16 * lda + k);
                acc[mi] = __builtin_amdgcn_mfma_f32_16x16x32_bf16(af, wf, acc[mi], 0, 0, 0);
            }
        }
    }

    int n = nt * 16 + col;
    float* base = part + (size_t)s * Bn * N;
#pragma unroll
    for (int mi = 0; mi < 4; ++mi) {
        if (mi < mtn) {
#pragma unroll
            for (int r = 0; r < 4; ++r) {
                int m = mi * 16 + quad * 4 + r;
                base[(size_t)m * N + n] = acc[mi][r];
            }
        }
    }
}

// ---------------- per-step kernels ----------------

// scores: fuses dec split-K reduction (+bias) in LDS, then relu-dot
__global__ void scores_kernel(const float* __restrict__ pdb, const float* __restrict__ bdec,
                              const unsigned short* __restrict__ encatt,
                              const float* __restrict__ wfull,
                              float* __restrict__ scores,
                              const int* __restrict__ nact, int t) {
    int b = blockIdx.y;
    if (b >= nact[t]) return;                   // inactive batch: outputs unused
    int tid = threadIdx.x;
    __shared__ float sdec[Ad];
    for (int i = tid; i < Ad; i += 256) {
        float v = bdec[i];
#pragma unroll
        for (int s2 = 0; s2 < 4; ++s2) v += pdb[((size_t)(s2 * Bn + b)) * 3072 + i];
        sdec[i] = v;
    }
    __syncthreads();
    int wave = tid >> 6, lane = tid & 63;
    int p = blockIdx.x * 4 + wave;              // 49*4 = 196
    const unsigned int* ea = (const unsigned int*)(encatt + ((size_t)(b * Pp + p) << 10));
    const float2* dp = (const float2*)sdec;
    const float2* wf = (const float2*)wfull;
    float acc = 0.f;
#pragma unroll
    for (int it = 0; it < 8; ++it) {
        int i2 = it * 64 + lane;
        unsigned int u = ea[i2];
        float2 dv = dp[i2];
        float2 wv = wf[i2];
        acc += fmaxf(bf2f((unsigned short)(u & 0xffffu)) + dv.x, 0.f) * wv.x;
        acc += fmaxf(bf2f((unsigned short)(u >> 16)) + dv.y, 0.f) * wv.y;
    }
    for (int o2 = 32; o2; o2 >>= 1) acc += __shfl_xor(acc, o2);
    if (lane == 0) scores[b * Pp + p] = acc;
}

// softmax (redundant per e-slice) + context + gate(reduce+sigmoid) + awe -> xh[t]
__global__ void softmaxctx_kernel(const float* __restrict__ scores,
                                  const float* __restrict__ pdb, const float* __restrict__ bbeta,
                                  const unsigned short* __restrict__ eo,
                                  unsigned short* __restrict__ xh_t,
                                  float* __restrict__ out_alpha,
                                  const int* __restrict__ nact, int t) {
    int b = blockIdx.y;
    if (b >= nact[t]) return;                   // inactive: alpha pre-zeroed, awe unused
    int tid = threadIdx.x;
    __shared__ float red[256];
    __shared__ float sal[Pp];
    float s = (tid < Pp) ? scores[b * Pp + tid] : -1e30f;
    red[tid] = s; __syncthreads();
    for (int o2 = 128; o2; o2 >>= 1) { if (tid < o2) red[tid] = fmaxf(red[tid], red[tid + o2]); __syncthreads(); }
    float mx = red[0]; __syncthreads();
    float e = (tid < Pp) ? expf(s - mx) : 0.f;
    red[tid] = e; __syncthreads();
    for (int o2 = 128; o2; o2 >>= 1) { if (tid < o2) red[tid] += red[tid + o2]; __syncthreads(); }
    float inv = 1.f / red[0];
    if (tid < Pp) {
        float a = e * inv;
        sal[tid] = a;
        if (blockIdx.x == 0) {
            out_alpha[((size_t)b * Td + t) * Pp + tid] = a;   // active => mask = 1
        }
    }
    __syncthreads();

    int e0 = blockIdx.x * 512 + tid * 2;
    const unsigned int* base = (const unsigned int*)(eo + (size_t)b * Pp * ENCd);
    int half = e0 >> 1;
    float a0 = 0.f, a1 = 0.f;
    for (int p = 0; p < Pp; ++p) {
        unsigned int u = base[p * (ENCd / 2) + half];
        float w = sal[p];
        a0 += w * bf2f((unsigned short)(u & 0xffffu));
        a1 += w * bf2f((unsigned short)(u >> 16));
    }
    float g0 = bbeta[e0], g1 = bbeta[e0 + 1];
#pragma unroll
    for (int s2 = 0; s2 < 4; ++s2) {
        const float* pb = pdb + ((size_t)(s2 * Bn + b)) * 3072 + Ad + e0;
        g0 += pb[0]; g1 += pb[1];
    }
    g0 = sigf(g0); g1 = sigf(g1);
    xh_t[(size_t)b * XHW + 512 + e0]     = f2bf(a0 * g0);
    xh_t[(size_t)b * XHW + 512 + e0 + 1] = f2bf(a1 * g1);
}

// LSTM: fuses gates split-K reduction (SK=8) + bias + pointwise; inactive batches
// just carry h forward (bf16 bit-copy), hall left unwritten (preds epilogue selects 0)
__global__ void lstm_kernel(const float* __restrict__ pg, const float* __restrict__ biascat,
                            float* __restrict__ c,
                            const unsigned short* __restrict__ xh_cur,
                            unsigned short* __restrict__ xh_next,
                            unsigned short* __restrict__ hall,
                            const int* __restrict__ nact, int t) {
    int id = blockIdx.x * 256 + threadIdx.x;    // < 64*1024
    int b = id >> 10, j = id & 1023;
    if (b >= nact[t]) {
        xh_next[(size_t)b * XHW + 2560 + j] = xh_cur[(size_t)b * XHW + 2560 + j];
        return;
    }
    float iv = biascat[j], fv = biascat[1024 + j], gv = biascat[2048 + j], ov = biascat[3072 + j];
#pragma unroll
    for (int s2 = 0; s2 < 8; ++s2) {
        const float* base = pg + ((size_t)(s2 * Bn + b)) * 4096;
        iv += base[j]; fv += base[1024 + j]; gv += base[2048 + j]; ov += base[3072 + j];
    }
    float co = c[id];
    float cn = sigf(fv) * co + sigf(iv) * tanhf(gv);
    float hn = sigf(ov) * tanhf(cn);
    unsigned short hb = f2bf(hn);
    c[id] = cn;                                  // active => mask = 1
    xh_next[(size_t)b * XHW + 2560 + j] = hb;
    hall[((size_t)t * Bn + b) * Hd + j] = hb;    // row m = t*64+b
}

// ---------------- host ----------------

extern "C" void kernel_launch(void* const* d_in, const int* in_sizes, int n_in,
                              void* d_out, int out_size, void* d_ws, size_t ws_size,
                              hipStream_t stream) {
    const float* enc_out   = (const float*)d_in[0];
    const int*   captions  = (const int*)d_in[1];
    const int*   lengths   = (const int*)d_in[2];
    const float* W_enc_att = (const float*)d_in[3];
    const float* b_enc_att = (const float*)d_in[4];
    const float* W_dec_att = (const float*)d_in[5];
    const float* b_dec_att = (const float*)d_in[6];
    const float* W_full    = (const float*)d_in[7];
    const float* emb       = (const float*)d_in[9];
    const float* W_ih      = (const float*)d_in[10];
    const float* b_ih      = (const float*)d_in[11];
    const float* W_hh      = (const float*)d_in[12];
    const float* b_hh      = (const float*)d_in[13];
    const float* W_init_h  = (const float*)d_in[14];
    const float* b_init_h  = (const float*)d_in[15];
    const float* W_init_c  = (const float*)d_in[16];
    const float* b_init_c  = (const float*)d_in[17];
    const float* W_beta    = (const float*)d_in[18];
    const float* b_beta    = (const float*)d_in[19];
    const float* W_fc      = (const float*)d_in[20];
    const float* b_fc      = (const float*)d_in[21];

    float* out       = (float*)d_out;
    float* out_pred  = out;                                    // (B,T,V)
    float* out_alpha = out + (size_t)Bn * Td * Vd;             // (B,T,P)
    float* out_caps  = out_alpha + (size_t)Bn * Td * Pp;       // (B,TC)
    float* out_dl    = out_caps + (size_t)Bn * TCd;            // (B,)
    float* out_ind   = out_dl + Bn;                            // (B,)

    char* ws = (char*)d_ws;
    size_t off = 0;
    auto take = [&](size_t n) -> char* {
        char* p = ws + off;
        off = (off + n + 255) & ~(size_t)255;
        return p;
    };
    int* ind_i   = (int*)take(Bn * 4);
    int* dl_i    = (int*)take(Bn * 4);
    int* nact_d  = (int*)take(Td * 4);
    unsigned short* eo_b     = (unsigned short*)take((size_t)Bn * Pp * ENCd * 2);   // 51.4 MB
    unsigned short* encatt_b = (unsigned short*)take((size_t)Bn * Pp * Ad * 2);     // 25.7 MB
    unsigned short* wcat_b   = (unsigned short*)take((size_t)4096 * XHW * 2);       // 29.4 MB
    unsigned short* wfc_b    = (unsigned short*)take((size_t)VPAD * Hd * 2);        // 21.0 MB (padded)
    unsigned short* wenc_b   = (unsigned short*)take((size_t)Ad * ENCd * 2);        // 8.4 MB
    unsigned short* wdb_b    = (unsigned short*)take((size_t)3072 * Hd * 2);        // 6.3 MB [wdec;wbeta]
    float*          biascat  = (float*)take(4096 * 4);
    float*          meanf    = (float*)take((size_t)Bn * ENCd * 4);
    unsigned short* xhbuf    = (unsigned short*)take((size_t)32 * Bn * XHW * 2);    // 14.7 MB
    float*          cbuf     = (float*)take((size_t)Bn * Hd * 4);
    unsigned short* hall     = (unsigned short*)take((size_t)2048 * Hd * 2);        // 4.2 MB (rows 1984..2047 pad)
    float*          scores   = (float*)take((size_t)Bn * Pp * 4);
    float*          pdb      = (float*)take((size_t)4 * Bn * 3072 * 4);             // 3.1 MB
    float*          pgates   = (float*)take((size_t)8 * Bn * 4096 * 4);             // 8.4 MB
    unsigned short* ahl      = (unsigned short*)take((size_t)Bn * KHL * 2);         // 0.8 MB
    // aliases (stream-ordered, lifetime-disjoint):
    unsigned short* whl   = encatt_b;   // 25.2 MB needed <= 25.7 MB; overwritten later by enc_att GEMM
    float*          pinit = pgates;     // 4.2 MB needed <= 8.4 MB; pgates first written in time loop
    (void)ws_size; (void)out_size; (void)n_in; (void)in_sizes;

    // ---- precompute ----
    sort_kernel<<<1, 64, 0, stream>>>(lengths, captions, ind_i, dl_i, out_caps, out_dl,
                                      out_ind, nact_d);
    zero_alpha_kernel<<<(Bn * Td * Pp + 255) / 256, 256, 0, stream>>>(out_alpha, Bn * Td * Pp);

    auto cvt = [&](const float* s, unsigned short* d, int n) {
        int g = (n + 255) / 256; if (g > 4096) g = 4096;
        cvt_kernel<<<g, 256, 0, stream>>>(s, d, n);
    };
    cvt(W_enc_att, wenc_b, Ad * ENCd);
    cvt(W_dec_att, wdb_b, Ad * Hd);                         // rows 0..1023
    cvt(W_beta,  wdb_b + (size_t)Ad * Hd, ENCd * Hd);       // rows 1024..3071
    cvt(W_fc,    wfc_b,   Vd * Hd);                         // rows 10000..10239 stay garbage (cols unused)
    wcat_kernel<<<dim3(14, 4096), 256, 0, stream>>>(W_ih, W_hh, wcat_b);
    biascat_kernel<<<16, 256, 0, stream>>>(b_ih, b_hh, biascat);

    gather_eo_kernel<<<dim3(1568, Bn), 256, 0, stream>>>(enc_out, ind_i, eo_b);
    mean_kernel<<<dim3(8, Bn), 256, 0, stream>>>(enc_out, ind_i, meanf);
    embs_kernel<<<dim3(62, Bn), 256, 0, stream>>>(emb, captions, ind_i, xhbuf);

    // h0/c0: hi/lo bf16 split-K GEMM (A'=[hi|lo|hi] 64xKHL, W'=[hi|hi|lo] 2048xKHL)
    hilo_w_kernel<<<dim3(8, 2048), 256, 0, stream>>>(W_init_h, W_init_c, whl);
    hilo_a_kernel<<<512, 256, 0, stream>>>(meanf, ahl);
    gemm_sk4<8><<<256, 256, 0, stream>>>(ahl, KHL, whl, 2048, KHL, pinit, nullptr, 0);
    initred_kernel<<<512, 256, 0, stream>>>(pinit, b_init_h, b_init_c, xhbuf, cbuf);

    // enc_att = eo @ W_enc_att^T + b -> bf16.  M=12544 (98 x 128-tiles), N=1024 (8 tiles)
    // SWZ=1: chunked XCD swizzle (FETCH 204 -> 48 MB verified round 6)
    gemm_tile<1, 1><<<98 * 8, 256, 0, stream>>>(eo_b, ENCd, wenc_b, ENCd, b_enc_att,
        Ad, 8, ENCd, nullptr, encatt_b, Ad, nullptr);

    // ---- time loop (active batches = b < nact[t], sorted desc) ----
    for (int t = 0; t < Td; ++t) {
        unsigned short* xh_t = xhbuf + (size_t)t * Bn * XHW;
        unsigned short* xh_n = xhbuf + (size_t)(t + 1) * Bn * XHW;

        // [dec | gate] partials: A = h slot, W = [wdec; wbeta], N=3072, K=1024, SK=4
        gemm_sk4<4><<<192, 256, 0, stream>>>(xh_t + 2560, XHW, wdb_b, 3072, Hd, pdb,
                                             nact_d, t);

        scores_kernel<<<dim3(49, Bn), 256, 0, stream>>>(pdb, b_dec_att, encatt_b, W_full,
                                                        scores, nact_d, t);

        softmaxctx_kernel<<<dim3(4, Bn), 256, 0, stream>>>(scores, pdb, b_beta, eo_b,
            xh_t, out_alpha, nact_d, t);

        // gates partials: A = xh[t], W = wcat, N=4096, K=3584, SK=8
        gemm_sk4<8><<<512, 256, 0, stream>>>(xh_t, XHW, wcat_b, 4096, XHW, pgates,
                                             nact_d, t);

        lstm_kernel<<<256, 256, 0, stream>>>(pgates, biascat, cbuf, xh_t, xh_n, hall,
                                             nact_d, t);
    }

    // batched preds: hall (2048 x 1024, rows m=t*64+b) @ W_fc^T -> d_out, select mask
    // M=2048 (16 x 128-tiles), N=10000 -> 80 x 128-tiles over padded 10240.
    // SWZ=0: nbn=80 default map already pins each B-panel to one XCD.
    gemm_tile<5, 0><<<16 * 80, 256, 0, stream>>>(hall, Hd, wfc_b, Hd, b_fc,
        Vd, 80, Hd, out_pred, nullptr, 0, dl_i);
}